// Round 15
// baseline (85.625 us; speedup 1.0000x reference)
//
#include <hip/hip_runtime.h>
#include <math.h>

#define IN_NODES 1152
#define OUT_NODES 10
#define IN_DIM 8
#define OUT_DIM 16
#define BATCH 256
#define KTILES 288       // K = 9216 = 288 tiles of 32
#define KC 16            // split-K chunks
#define KT_PER_KC 18     // 288 / 16
#define NBT 16           // b-tiles of 16

typedef __attribute__((ext_vector_type(8))) short bf16x8;
typedef __attribute__((ext_vector_type(4))) float f32x4;

__device__ __forceinline__ unsigned short f2bf(float f) {
    unsigned u = __float_as_uint(f);
    u += 0x7FFF + ((u >> 16) & 1);   // round-to-nearest-even
    return (unsigned short)(u >> 16);
}

// ---------------------------------------------------------------------------
// Pack layouts (validated rounds 5/8/9/10/13/14):
//  B slot sl = (bt*KTILES + kt)*64 + lane, lane = (i&3)*16 + (b&15), elem = k.
//  A slot s  = (j*KTILES + kt)*64 + lane, lane = (i&3)*16 + d, elem = k.
//  C tile:   col = lane&15 (b), row = (lane>>4)*4 + r (d).
// Precision: A and B single bf16 (RNE); measured absmax 0.0039 (thr 0.0159).
// ---------------------------------------------------------------------------

// k_prep: blocks 0..1151: xr + B-pack.  blocks 1152..1871: A-pack (c = 0.1).
__global__ __launch_bounds__(256) void k_prep(const float* __restrict__ x,
                                              const float* __restrict__ W,
                                              float* __restrict__ xr,
                                              unsigned short* __restrict__ Bhi,
                                              unsigned short* __restrict__ Ahi) {
    const int bid = blockIdx.x;
    const int tid = threadIdx.x;
    if (bid < IN_NODES) {
        const int i = bid, b = tid;
        const float4* xp = (const float4*)(x + ((size_t)b * IN_NODES + i) * IN_DIM);
        float4 a0 = xp[0], a1 = xp[1];
        float4* xd = (float4*)(xr + ((size_t)i * BATCH + b) * IN_DIM);
        xd[0] = a0; xd[1] = a1;
        float vals[8] = {a0.x, a0.y, a0.z, a0.w, a1.x, a1.y, a1.z, a1.w};
        bf16x8 vh;
#pragma unroll
        for (int e = 0; e < 8; ++e) vh[e] = (short)f2bf(vals[e]);
        size_t sl = ((size_t)(b >> 4) * KTILES + (i >> 2)) * 64 + (i & 3) * 16 + (b & 15);
        *(bf16x8*)(Bhi + sl * 8) = vh;
    } else {
        const int s = (bid - IN_NODES) * 256 + tid;   // 0..184319
        const int j = s / (KTILES * 64);
        const int rem = s % (KTILES * 64);
        const int kt = rem >> 6;
        const int l = rem & 63;
        const int i = kt * 4 + (l >> 4);
        const int d = l & 15;
        const float4* wp = (const float4*)(W +
            (((size_t)i * OUT_NODES + j) * OUT_DIM + d) * IN_DIM);
        float4 w0 = wp[0], w1 = wp[1];
        const float c = 1.0f / OUT_NODES;
        float vals[8] = {c * w0.x, c * w0.y, c * w0.z, c * w0.w,
                         c * w1.x, c * w1.y, c * w1.z, c * w1.w};
        bf16x8 vh;
#pragma unroll
        for (int e = 0; e < 8; ++e) vh[e] = (short)f2bf(vals[e]);
        *(bf16x8*)(Ahi + (size_t)s * 8) = vh;
    }
}

// ---------------------------------------------------------------------------
// k_gemm: grid 640 = (j=10, btg=4, kc=16), 256 thr (4 waves, wave -> bt).
// 1 MFMA/ktile, 2 acc chains. Fence-free split-K partials. (validated r14)
// ---------------------------------------------------------------------------
__global__ __launch_bounds__(256) void k_gemm(const unsigned short* __restrict__ Ahi,
                                              const unsigned short* __restrict__ Bhi,
                                              float* __restrict__ part) {
    const int bid = blockIdx.x;
    const int j = bid >> 6;            // /64
    const int r = bid & 63;
    const int btg = r >> 4;
    const int kc = r & 15;
    const int tid = threadIdx.x;
    const int lane = tid & 63;
    const int bt = btg * 4 + (tid >> 6);

    const size_t ab = (((size_t)j * KTILES + kc * KT_PER_KC) * 64 + lane) * 8;
    const size_t bb = (((size_t)bt * KTILES + kc * KT_PER_KC) * 64 + lane) * 8;

    f32x4 acc0 = {0.f, 0.f, 0.f, 0.f}, acc1 = acc0;
#pragma unroll
    for (int kt = 0; kt < KT_PER_KC; kt += 2) {
        bf16x8 a0 = *(const bf16x8*)(Ahi + ab + (size_t)kt * 512);
        bf16x8 b0 = *(const bf16x8*)(Bhi + bb + (size_t)kt * 512);
        bf16x8 a1 = *(const bf16x8*)(Ahi + ab + (size_t)(kt + 1) * 512);
        bf16x8 b1 = *(const bf16x8*)(Bhi + bb + (size_t)(kt + 1) * 512);
        acc0 = __builtin_amdgcn_mfma_f32_16x16x32_bf16(a0, b0, acc0, 0, 0, 0);
        acc1 = __builtin_amdgcn_mfma_f32_16x16x32_bf16(a1, b1, acc1, 0, 0, 0);
    }
    f32x4 acc = acc0 + acc1;
    *(f32x4*)(part + (((size_t)kc * OUT_NODES + j) * NBT + bt) * 1024 + lane * 4) = acc;
}

// ---------------------------------------------------------------------------
// k_reduce: grid 160 = (j,bt), 256 thr = 4 waves; wave w sums kc 4w..4w+3,
// fixed-order LDS combine -> squash -> v/out. Deterministic tree.
// ---------------------------------------------------------------------------
__global__ __launch_bounds__(256) void k_reduce(const float* __restrict__ part,
                                                float* __restrict__ v,
                                                float* __restrict__ out,
                                                int write_out) {
    __shared__ __align__(16) float red[4][64][4];
    const int j = blockIdx.x >> 4;
    const int bt = blockIdx.x & 15;
    const int w = threadIdx.x >> 6;
    const int lane = threadIdx.x & 63;

    f32x4 s = {0.f, 0.f, 0.f, 0.f};
#pragma unroll
    for (int q = 0; q < 4; ++q) {
        int kc = w * 4 + q;
        s += *(const f32x4*)(part + (((size_t)kc * OUT_NODES + j) * NBT + bt) * 1024 +
                             lane * 4);
    }
    *(f32x4*)&red[w][lane][0] = s;
    __syncthreads();

    if (w == 0) {
        f32x4 t0 = *(const f32x4*)&red[0][lane][0];
        f32x4 t1 = *(const f32x4*)&red[1][lane][0];
        f32x4 t2 = *(const f32x4*)&red[2][lane][0];
        f32x4 t3 = *(const f32x4*)&red[3][lane][0];
        f32x4 sv = (t0 + t1) + (t2 + t3);
        float sq = sv[0] * sv[0] + sv[1] * sv[1] + sv[2] * sv[2] + sv[3] * sv[3];
        sq += __shfl_xor(sq, 16);
        sq += __shfl_xor(sq, 32);
        float scale = sq / ((1.0f + sq) * sqrtf(sq));
        f32x4 vv = sv * scale;
        const int b = bt * 16 + (lane & 15);
        const int d0 = (lane >> 4) * 4;
        *(f32x4*)(v + ((size_t)j * BATCH + b) * OUT_DIM + d0) = vv;
        if (write_out)
            *(f32x4*)(out + ((size_t)b * OUT_NODES + j) * OUT_DIM + d0) = vv;
    }
}

// ---------------------------------------------------------------------------
// k_agree: b-parallel. grid 1152 (block=i), 256 thr (b).
// W rows read as WAVE-UNIFORM global derefs (i=blockIdx, j/d unroll consts)
// -> compiler scalarizes to s_load; kills the 320 LDS broadcast reads of r10.
// Then wave+LDS reduce; softmax; c*W -> A-pack fold (coalesced global W).
// ---------------------------------------------------------------------------
__global__ __launch_bounds__(256) void k_agree(const float* __restrict__ W,
                                               const float* __restrict__ xr,
                                               const float* __restrict__ v,
                                               float* __restrict__ blog,
                                               unsigned short* __restrict__ Ahi,
                                               int it) {
    __shared__ float red[4][OUT_NODES];
    __shared__ float csh[OUT_NODES];

    const int i = blockIdx.x;
    const int tid = threadIdx.x;
    const int w = tid >> 6, lane = tid & 63;
    const float* __restrict__ Wi = W + (size_t)i * 1280;   // block-uniform base

    const int b = tid;
    const float4* xp = (const float4*)(xr + ((size_t)i * BATCH + b) * IN_DIM);
    const float4 x0 = xp[0], x1 = xp[1];

#pragma unroll 2
    for (int j = 0; j < OUT_NODES; ++j) {
        const float4* vp = (const float4*)(v + ((size_t)j * BATCH + b) * OUT_DIM);
        float4 v0 = vp[0], v1 = vp[1], v2 = vp[2], v3 = vp[3];
        float vv[16] = {v0.x, v0.y, v0.z, v0.w, v1.x, v1.y, v1.z, v1.w,
                        v2.x, v2.y, v2.z, v2.w, v3.x, v3.y, v3.z, v3.w};
        float s0 = 0.f, s1 = 0.f, s2 = 0.f, s3 = 0.f;
#pragma unroll
        for (int d = 0; d < OUT_DIM; ++d) {
            // wave-uniform address -> scalar loads
            const float* wr = Wi + (j * 16 + d) * 8;
            float u = wr[0] * x0.x;
            u = fmaf(wr[1], x0.y, u); u = fmaf(wr[2], x0.z, u);
            u = fmaf(wr[3], x0.w, u); u = fmaf(wr[4], x1.x, u);
            u = fmaf(wr[5], x1.y, u); u = fmaf(wr[6], x1.z, u);
            u = fmaf(wr[7], x1.w, u);
            if ((d & 3) == 0) s0 = fmaf(u, vv[d], s0);
            else if ((d & 3) == 1) s1 = fmaf(u, vv[d], s1);
            else if ((d & 3) == 2) s2 = fmaf(u, vv[d], s2);
            else s3 = fmaf(u, vv[d], s3);
        }
        float sum = (s0 + s1) + (s2 + s3);
        sum += __shfl_xor(sum, 1);
        sum += __shfl_xor(sum, 2);
        sum += __shfl_xor(sum, 4);
        sum += __shfl_xor(sum, 8);
        sum += __shfl_xor(sum, 16);
        sum += __shfl_xor(sum, 32);
        if (lane == 0) red[w][j] = sum;
    }
    __syncthreads();

    if (tid < OUT_NODES) {
        float a = (red[0][tid] + red[1][tid]) + (red[2][tid] + red[3][tid]);
        float bn = (it == 0 ? 0.f : blog[i * OUT_NODES + tid]) + a * (1.0f / BATCH);
        if (it == 0) blog[i * OUT_NODES + tid] = bn;
        red[0][tid] = bn;                 // reuse red row 0 for logits
    }
    __syncthreads();

    if (tid < OUT_NODES) {
        float m = red[0][0];
#pragma unroll
        for (int jj = 1; jj < OUT_NODES; ++jj) m = fmaxf(m, red[0][jj]);
        float ssum = 0.f;
#pragma unroll
        for (int jj = 0; jj < OUT_NODES; ++jj) ssum += __expf(red[0][jj] - m);
        csh[tid] = __expf(red[0][tid] - m) / ssum;
    }
    __syncthreads();

    // fold c*W -> A-pack: threads 0..159, j = t>>4, d = t&15 (coalesced W reads)
    if (tid < OUT_NODES * OUT_DIM) {
        const int j = tid >> 4;
        const int d = tid & 15;
        const float c = csh[j];
        const float4* wp = (const float4*)(Wi + (j * 16 + d) * 8);
        float4 w0 = wp[0], w1 = wp[1];
        float vals[8] = {c * w0.x, c * w0.y, c * w0.z, c * w0.w,
                         c * w1.x, c * w1.y, c * w1.z, c * w1.w};
        bf16x8 vh;
#pragma unroll
        for (int e = 0; e < 8; ++e) vh[e] = (short)f2bf(vals[e]);
        size_t sl = ((size_t)j * KTILES + (i >> 2)) * 64 + (i & 3) * 16 + d;
        *(bf16x8*)(Ahi + sl * 8) = vh;
    }
}

// ---------------------------------------------------------------------------
extern "C" void kernel_launch(void* const* d_in, const int* in_sizes, int n_in,
                              void* d_out, int out_size, void* d_ws, size_t ws_size,
                              hipStream_t stream) {
    const float* x = (const float*)d_in[0];  // [256,1152,8]
    const float* W = (const float*)d_in[1];  // [1152,10,16,8]
    float* out = (float*)d_out;              // [256,10,16,1]

    char* p = (char*)d_ws;
    float* xr = (float*)p;                     p += (size_t)IN_NODES * BATCH * IN_DIM * 4;
    unsigned short* Bhi = (unsigned short*)p;  p += (size_t)NBT * KTILES * 64 * 8 * 2;
    unsigned short* Ahi = (unsigned short*)p;  p += (size_t)OUT_NODES * KTILES * 64 * 8 * 2;
    float* part = (float*)p;                   p += (size_t)KC * OUT_NODES * NBT * 1024 * 4;
    float* v = (float*)p;                      p += (size_t)OUT_NODES * BATCH * OUT_DIM * 4;
    float* blog = (float*)p;                   p += (size_t)IN_NODES * OUT_NODES * 4;
    // total ~28 MB of ws

    k_prep<<<IN_NODES + 720, 256, 0, stream>>>(x, W, xr, Bhi, Ahi);

    for (int it = 0; it < 3; ++it) {
        k_gemm<<<640, 256, 0, stream>>>(Ahi, Bhi, part);
        k_reduce<<<160, 256, 0, stream>>>(part, v, out, it == 2 ? 1 : 0);
        if (it < 2)
            k_agree<<<IN_NODES, 256, 0, stream>>>(W, xr, v, blog, Ahi, it);
    }
}

// Round 16
// 79.361 us; speedup vs baseline: 1.0789x; 1.0789x over previous
//
#include <hip/hip_runtime.h>
#include <math.h>

#define IN_NODES 1152
#define OUT_NODES 10
#define IN_DIM 8
#define OUT_DIM 16
#define BATCH 256
#define KTILES 288       // K = 9216 = 288 tiles of 32
#define KC 16            // split-K chunks
#define KT_PER_KC 18     // 288 / 16
#define NBT 16           // b-tiles of 16

typedef __attribute__((ext_vector_type(8))) short bf16x8;
typedef __attribute__((ext_vector_type(4))) float f32x4;

__device__ __forceinline__ unsigned short f2bf(float f) {
    unsigned u = __float_as_uint(f);
    u += 0x7FFF + ((u >> 16) & 1);   // round-to-nearest-even
    return (unsigned short)(u >> 16);
}
__device__ __forceinline__ float bf2f(unsigned short h) {
    return __uint_as_float(((unsigned)h) << 16);
}

// async global->LDS, 16B per lane
__device__ __forceinline__ void ld16(const void* g, void* l) {
    __builtin_amdgcn_global_load_lds(
        (const __attribute__((address_space(1))) unsigned int*)g,
        (__attribute__((address_space(3))) unsigned int*)l, 16, 0, 0);
}

// ---------------------------------------------------------------------------
// Pack layouts (validated rounds 5/8/9/10/13/14):
//  B slot sl = (bt*KTILES + kt)*64 + lane, lane = (i&3)*16 + (b&15), elem = k.
//  A slot s  = (j*KTILES + kt)*64 + lane, lane = (i&3)*16 + d, elem = k.
//  C tile:   col = lane&15 (b), row = (lane>>4)*4 + r (d).
// Precision: A and B single bf16 (RNE); r14 measured absmax 0.0039 (thr 0.0159).
// x is consumed ONLY as bf16 (Bhi) — xr buffer eliminated this round; the
// logits path now also uses bf16 x (delta-c ~1e-3 relative, well in budget).
// ---------------------------------------------------------------------------

// k_prep: blocks 0..1151: B-pack.  blocks 1152..1871: A-pack (c = 0.1).
__global__ __launch_bounds__(256) void k_prep(const float* __restrict__ x,
                                              const float* __restrict__ W,
                                              unsigned short* __restrict__ Bhi,
                                              unsigned short* __restrict__ Ahi) {
    const int bid = blockIdx.x;
    const int tid = threadIdx.x;
    if (bid < IN_NODES) {
        const int i = bid, b = tid;
        const float4* xp = (const float4*)(x + ((size_t)b * IN_NODES + i) * IN_DIM);
        float4 a0 = xp[0], a1 = xp[1];
        float vals[8] = {a0.x, a0.y, a0.z, a0.w, a1.x, a1.y, a1.z, a1.w};
        bf16x8 vh;
#pragma unroll
        for (int e = 0; e < 8; ++e) vh[e] = (short)f2bf(vals[e]);
        size_t sl = ((size_t)(b >> 4) * KTILES + (i >> 2)) * 64 + (i & 3) * 16 + (b & 15);
        *(bf16x8*)(Bhi + sl * 8) = vh;
    } else {
        const int s = (bid - IN_NODES) * 256 + tid;   // 0..184319
        const int j = s / (KTILES * 64);
        const int rem = s % (KTILES * 64);
        const int kt = rem >> 6;
        const int l = rem & 63;
        const int i = kt * 4 + (l >> 4);
        const int d = l & 15;
        const float4* wp = (const float4*)(W +
            (((size_t)i * OUT_NODES + j) * OUT_DIM + d) * IN_DIM);
        float4 w0 = wp[0], w1 = wp[1];
        const float c = 1.0f / OUT_NODES;
        float vals[8] = {c * w0.x, c * w0.y, c * w0.z, c * w0.w,
                         c * w1.x, c * w1.y, c * w1.z, c * w1.w};
        bf16x8 vh;
#pragma unroll
        for (int e = 0; e < 8; ++e) vh[e] = (short)f2bf(vals[e]);
        *(bf16x8*)(Ahi + (size_t)s * 8) = vh;
    }
}

// ---------------------------------------------------------------------------
// k_gemm: grid 640 = (j=10, btg=4, kc=16), 256 thr (4 waves, wave -> bt).
// 1 MFMA/ktile, 2 acc chains. Fence-free split-K partials. (validated r14)
// ---------------------------------------------------------------------------
__global__ __launch_bounds__(256) void k_gemm(const unsigned short* __restrict__ Ahi,
                                              const unsigned short* __restrict__ Bhi,
                                              float* __restrict__ part) {
    const int bid = blockIdx.x;
    const int j = bid >> 6;            // /64
    const int r = bid & 63;
    const int btg = r >> 4;
    const int kc = r & 15;
    const int tid = threadIdx.x;
    const int lane = tid & 63;
    const int bt = btg * 4 + (tid >> 6);

    const size_t ab = (((size_t)j * KTILES + kc * KT_PER_KC) * 64 + lane) * 8;
    const size_t bb = (((size_t)bt * KTILES + kc * KT_PER_KC) * 64 + lane) * 8;

    f32x4 acc0 = {0.f, 0.f, 0.f, 0.f}, acc1 = acc0;
#pragma unroll
    for (int kt = 0; kt < KT_PER_KC; kt += 2) {
        bf16x8 a0 = *(const bf16x8*)(Ahi + ab + (size_t)kt * 512);
        bf16x8 b0 = *(const bf16x8*)(Bhi + bb + (size_t)kt * 512);
        bf16x8 a1 = *(const bf16x8*)(Ahi + ab + (size_t)(kt + 1) * 512);
        bf16x8 b1 = *(const bf16x8*)(Bhi + bb + (size_t)(kt + 1) * 512);
        acc0 = __builtin_amdgcn_mfma_f32_16x16x32_bf16(a0, b0, acc0, 0, 0, 0);
        acc1 = __builtin_amdgcn_mfma_f32_16x16x32_bf16(a1, b1, acc1, 0, 0, 0);
    }
    f32x4 acc = acc0 + acc1;
    *(f32x4*)(part + (((size_t)kc * OUT_NODES + j) * NBT + bt) * 1024 + lane * 4) = acc;
}

// ---------------------------------------------------------------------------
// k_reduce: grid 160 = (j,bt), 64 thr. Sum over kc (fixed order) + squash.
// (validated round 14)
// ---------------------------------------------------------------------------
__global__ __launch_bounds__(64) void k_reduce(const float* __restrict__ part,
                                               float* __restrict__ v,
                                               float* __restrict__ out,
                                               int write_out) {
    const int j = blockIdx.x >> 4;
    const int bt = blockIdx.x & 15;
    const int lane = threadIdx.x;

    f32x4 s = {0.f, 0.f, 0.f, 0.f};
#pragma unroll
    for (int kc = 0; kc < KC; ++kc)
        s += *(const f32x4*)(part + (((size_t)kc * OUT_NODES + j) * NBT + bt) * 1024 +
                             lane * 4);
    float sq = s[0] * s[0] + s[1] * s[1] + s[2] * s[2] + s[3] * s[3];
    sq += __shfl_xor(sq, 16);
    sq += __shfl_xor(sq, 32);
    float scale = sq / ((1.0f + sq) * sqrtf(sq));
    f32x4 vv = s * scale;
    const int b = bt * 16 + (lane & 15);
    const int d0 = (lane >> 4) * 4;
    *(f32x4*)(v + ((size_t)j * BATCH + b) * OUT_DIM + d0) = vv;
    if (write_out)
        *(f32x4*)(out + ((size_t)b * OUT_NODES + j) * OUT_DIM + d0) = vv;
}

// ---------------------------------------------------------------------------
// k_agree: b-parallel (round-14 structure: LDS-staged W). grid 1152 (block=i),
// 256 thr (b). x read as bf16 from Bhi (16B/thread, 256B-contiguous per
// 16-lane group). Wave+LDS reduce; softmax; c*W -> A-pack fold.
// ---------------------------------------------------------------------------
__global__ __launch_bounds__(256) void k_agree(const float* __restrict__ W,
                                               const unsigned short* __restrict__ Bhi,
                                               const float* __restrict__ v,
                                               float* __restrict__ blog,
                                               unsigned short* __restrict__ Ahi,
                                               int it) {
    __shared__ __align__(16) float W_s[1280];
    __shared__ float red[4][OUT_NODES];
    __shared__ float csh[OUT_NODES];

    const int i = blockIdx.x;
    const int tid = threadIdx.x;
    const int w = tid >> 6, lane = tid & 63;

    {
        const char* gw = (const char*)W + (size_t)i * 5120;
        ld16(gw + tid * 16, (char*)W_s + tid * 16);
        if (tid < 64) ld16(gw + 4096 + tid * 16, (char*)W_s + 4096 + tid * 16);
    }

    // x (bf16) for this thread's b, from the B-pack
    const int b = tid;
    float xf[8];
    {
        size_t sl = ((size_t)(b >> 4) * KTILES + (i >> 2)) * 64 + (i & 3) * 16 + (b & 15);
        bf16x8 xv = *(const bf16x8*)(Bhi + sl * 8);
#pragma unroll
        for (int e = 0; e < 8; ++e) xf[e] = bf2f((unsigned short)xv[e]);
    }

    asm volatile("s_waitcnt vmcnt(0)" ::: "memory");
    __syncthreads();

#pragma unroll 2
    for (int j = 0; j < OUT_NODES; ++j) {
        const float4* vp = (const float4*)(v + ((size_t)j * BATCH + b) * OUT_DIM);
        float4 v0 = vp[0], v1 = vp[1], v2 = vp[2], v3 = vp[3];
        float vv[16] = {v0.x, v0.y, v0.z, v0.w, v1.x, v1.y, v1.z, v1.w,
                        v2.x, v2.y, v2.z, v2.w, v3.x, v3.y, v3.z, v3.w};
        float s0 = 0.f, s1 = 0.f, s2 = 0.f, s3 = 0.f;
#pragma unroll
        for (int d = 0; d < OUT_DIM; ++d) {
            float4 w0 = *(const float4*)&W_s[(j * 16 + d) * 8];
            float4 w1 = *(const float4*)&W_s[(j * 16 + d) * 8 + 4];
            float u = w0.x * xf[0];
            u = fmaf(w0.y, xf[1], u); u = fmaf(w0.z, xf[2], u);
            u = fmaf(w0.w, xf[3], u); u = fmaf(w1.x, xf[4], u);
            u = fmaf(w1.y, xf[5], u); u = fmaf(w1.z, xf[6], u);
            u = fmaf(w1.w, xf[7], u);
            if ((d & 3) == 0) s0 = fmaf(u, vv[d], s0);
            else if ((d & 3) == 1) s1 = fmaf(u, vv[d], s1);
            else if ((d & 3) == 2) s2 = fmaf(u, vv[d], s2);
            else s3 = fmaf(u, vv[d], s3);
        }
        float sum = (s0 + s1) + (s2 + s3);
        sum += __shfl_xor(sum, 1);
        sum += __shfl_xor(sum, 2);
        sum += __shfl_xor(sum, 4);
        sum += __shfl_xor(sum, 8);
        sum += __shfl_xor(sum, 16);
        sum += __shfl_xor(sum, 32);
        if (lane == 0) red[w][j] = sum;
    }
    __syncthreads();

    if (tid < OUT_NODES) {
        float a = (red[0][tid] + red[1][tid]) + (red[2][tid] + red[3][tid]);
        float bn = (it == 0 ? 0.f : blog[i * OUT_NODES + tid]) + a * (1.0f / BATCH);
        if (it == 0) blog[i * OUT_NODES + tid] = bn;
        red[0][tid] = bn;                 // reuse red row 0 for logits
    }
    __syncthreads();

    if (tid < OUT_NODES) {
        float m = red[0][0];
#pragma unroll
        for (int jj = 1; jj < OUT_NODES; ++jj) m = fmaxf(m, red[0][jj]);
        float ssum = 0.f;
#pragma unroll
        for (int jj = 0; jj < OUT_NODES; ++jj) ssum += __expf(red[0][jj] - m);
        csh[tid] = __expf(red[0][tid] - m) / ssum;
    }
    __syncthreads();

    // fold c*W -> A-pack: threads 0..159, j = t>>4, d = t&15 (W from LDS)
    if (tid < OUT_NODES * OUT_DIM) {
        const int j = tid >> 4;
        const int d = tid & 15;
        const float c = csh[j];
        const float* wrow = &W_s[(j * 16 + d) * 8];
        bf16x8 vh;
#pragma unroll
        for (int e = 0; e < 8; ++e) vh[e] = (short)f2bf(c * wrow[e]);
        size_t sl = ((size_t)j * KTILES + (i >> 2)) * 64 + (i & 3) * 16 + d;
        *(bf16x8*)(Ahi + sl * 8) = vh;
    }
}

// ---------------------------------------------------------------------------
extern "C" void kernel_launch(void* const* d_in, const int* in_sizes, int n_in,
                              void* d_out, int out_size, void* d_ws, size_t ws_size,
                              hipStream_t stream) {
    const float* x = (const float*)d_in[0];  // [256,1152,8]
    const float* W = (const float*)d_in[1];  // [1152,10,16,8]
    float* out = (float*)d_out;              // [256,10,16,1]

    char* p = (char*)d_ws;
    unsigned short* Bhi = (unsigned short*)p;  p += (size_t)NBT * KTILES * 64 * 8 * 2;
    unsigned short* Ahi = (unsigned short*)p;  p += (size_t)OUT_NODES * KTILES * 64 * 8 * 2;
    float* part = (float*)p;                   p += (size_t)KC * OUT_NODES * NBT * 1024 * 4;
    float* v = (float*)p;                      p += (size_t)OUT_NODES * BATCH * OUT_DIM * 4;
    float* blog = (float*)p;                   p += (size_t)IN_NODES * OUT_NODES * 4;
    // total ~19 MB of ws

    k_prep<<<IN_NODES + 720, 256, 0, stream>>>(x, W, Bhi, Ahi);

    for (int it = 0; it < 3; ++it) {
        k_gemm<<<640, 256, 0, stream>>>(Ahi, Bhi, part);
        k_reduce<<<160, 64, 0, stream>>>(part, v, out, it == 2 ? 1 : 0);
        if (it < 2)
            k_agree<<<IN_NODES, 256, 0, stream>>>(W, Bhi, v, blog, Ahi, it);
    }
}

// Round 17
// 67.782 us; speedup vs baseline: 1.2632x; 1.1708x over previous
//
#include <hip/hip_runtime.h>
#include <math.h>

#define IN_NODES 1152
#define OUT_NODES 10
#define IN_DIM 8
#define OUT_DIM 16
#define BATCH 256
#define KTILES 288       // K = 9216 = 288 tiles of 32 (main GEMM)
#define KC 16            // split-K chunks
#define KT_PER_KC 18     // 288 / 16
#define NBT 16           // b-tiles of 16
#define MT 576           // m-tiles of 16 over ik = 9216 (agree M-GEMM)

typedef __attribute__((ext_vector_type(8))) short bf16x8;
typedef __attribute__((ext_vector_type(4))) float f32x4;

__device__ __forceinline__ unsigned short f2bf(float f) {
    unsigned u = __float_as_uint(f);
    u += 0x7FFF + ((u >> 16) & 1);   // round-to-nearest-even
    return (unsigned short)(u >> 16);
}

// ---------------------------------------------------------------------------
// Fragment conventions (validated r5/r8/r9/r10/r13/r14):
//  A-frag: lane&15 = m, K = (lane>>4)*8 + e.   B-frag: lane&15 = n, same K.
//  C tile: col = lane&15 (n), row = (lane>>4)*4 + r (m).
// Packs:
//  Bhi  [bt][kt][lane][e]: n=b (lane&15), K=(i&3)*8+k       (main GEMM B)
//  Ahi  [j][kt][lane][e]:  m=d (lane&15), K=(i&3)*8+k       (main GEMM A)
//  Axt  [mt][bk][lane][e]: m=ik (lane&15), K=b&31           (M-GEMM A)
//  Bv   [j][bk][lane][e]:  n=d (lane&15),  K=b&31           (M-GEMM B)
// Precision: all packs bf16 RNE; r16 measured absmax 0.0039 (thr 0.0159);
// bf16 v in logits adds ~0.2% c-perturbation (budgeted).
// ---------------------------------------------------------------------------

// k_prep: [0,1152): Bhi. [1152,1872): Ahi (c = 0.1). [1872,2160): Axt.
__global__ __launch_bounds__(256) void k_prep(const float* __restrict__ x,
                                              const float* __restrict__ W,
                                              unsigned short* __restrict__ Bhi,
                                              unsigned short* __restrict__ Ahi,
                                              unsigned short* __restrict__ Axt) {
    const int bid = blockIdx.x;
    const int tid = threadIdx.x;
    if (bid < IN_NODES) {
        const int i = bid, b = tid;
        const float4* xp = (const float4*)(x + ((size_t)b * IN_NODES + i) * IN_DIM);
        float4 a0 = xp[0], a1 = xp[1];
        float vals[8] = {a0.x, a0.y, a0.z, a0.w, a1.x, a1.y, a1.z, a1.w};
        bf16x8 vh;
#pragma unroll
        for (int e = 0; e < 8; ++e) vh[e] = (short)f2bf(vals[e]);
        size_t sl = ((size_t)(b >> 4) * KTILES + (i >> 2)) * 64 + (i & 3) * 16 + (b & 15);
        *(bf16x8*)(Bhi + sl * 8) = vh;
    } else if (bid < IN_NODES + 720) {
        const int s = (bid - IN_NODES) * 256 + tid;   // 0..184319
        const int j = s / (KTILES * 64);
        const int rem = s % (KTILES * 64);
        const int kt = rem >> 6;
        const int l = rem & 63;
        const int i = kt * 4 + (l >> 4);
        const int d = l & 15;
        const float4* wp = (const float4*)(W +
            (((size_t)i * OUT_NODES + j) * OUT_DIM + d) * IN_DIM);
        float4 w0 = wp[0], w1 = wp[1];
        const float c = 1.0f / OUT_NODES;
        float vals[8] = {c * w0.x, c * w0.y, c * w0.z, c * w0.w,
                         c * w1.x, c * w1.y, c * w1.z, c * w1.w};
        bf16x8 vh;
#pragma unroll
        for (int e = 0; e < 8; ++e) vh[e] = (short)f2bf(vals[e]);
        *(bf16x8*)(Ahi + (size_t)s * 8) = vh;
    } else {
        const int n = bid - (IN_NODES + 720);        // 0..287
#pragma unroll
        for (int p = 0; p < 4; ++p) {
            const int q = p * 256 + tid;             // 0..1023
            const int mt = n * 2 + (q >> 9);
            const int rem = q & 511;
            const int bk = rem >> 6;
            const int lane = rem & 63;
            const int ik = mt * 16 + (lane & 15);
            const int i = ik >> 3, k = ik & 7;
            const int b0 = bk * 32 + (lane >> 4) * 8;
            bf16x8 vh;
#pragma unroll
            for (int e = 0; e < 8; ++e)
                vh[e] = (short)f2bf(x[((size_t)(b0 + e) * IN_NODES + i) * IN_DIM + k]);
            *(bf16x8*)(Axt + (((size_t)mt * 8 + bk) * 64 + lane) * 8) = vh;
        }
    }
}

// ---------------------------------------------------------------------------
// k_gemm: grid 640 = (j=10, btg=4, kc=16), 256 thr. (validated r14)
// ---------------------------------------------------------------------------
__global__ __launch_bounds__(256) void k_gemm(const unsigned short* __restrict__ Ahi,
                                              const unsigned short* __restrict__ Bhi,
                                              float* __restrict__ part) {
    const int bid = blockIdx.x;
    const int j = bid >> 6;
    const int r = bid & 63;
    const int btg = r >> 4;
    const int kc = r & 15;
    const int tid = threadIdx.x;
    const int lane = tid & 63;
    const int bt = btg * 4 + (tid >> 6);

    const size_t ab = (((size_t)j * KTILES + kc * KT_PER_KC) * 64 + lane) * 8;
    const size_t bb = (((size_t)bt * KTILES + kc * KT_PER_KC) * 64 + lane) * 8;

    f32x4 acc0 = {0.f, 0.f, 0.f, 0.f}, acc1 = acc0;
#pragma unroll
    for (int kt = 0; kt < KT_PER_KC; kt += 2) {
        bf16x8 a0 = *(const bf16x8*)(Ahi + ab + (size_t)kt * 512);
        bf16x8 b0 = *(const bf16x8*)(Bhi + bb + (size_t)kt * 512);
        bf16x8 a1 = *(const bf16x8*)(Ahi + ab + (size_t)(kt + 1) * 512);
        bf16x8 b1 = *(const bf16x8*)(Bhi + bb + (size_t)(kt + 1) * 512);
        acc0 = __builtin_amdgcn_mfma_f32_16x16x32_bf16(a0, b0, acc0, 0, 0, 0);
        acc1 = __builtin_amdgcn_mfma_f32_16x16x32_bf16(a1, b1, acc1, 0, 0, 0);
    }
    f32x4 acc = acc0 + acc1;
    *(f32x4*)(part + (((size_t)kc * OUT_NODES + j) * NBT + bt) * 1024 + lane * 4) = acc;
}

// ---------------------------------------------------------------------------
// k_reduce: grid 160 = (j,bt), 64 thr. Sum over kc + squash -> Bv (bf16
// B-frag pack for the agree M-GEMM) and out (final iter).
// ---------------------------------------------------------------------------
__global__ __launch_bounds__(64) void k_reduce(const float* __restrict__ part,
                                               unsigned short* __restrict__ Bv,
                                               float* __restrict__ out,
                                               int write_out) {
    const int j = blockIdx.x >> 4;
    const int bt = blockIdx.x & 15;
    const int lane = threadIdx.x;

    f32x4 s = {0.f, 0.f, 0.f, 0.f};
#pragma unroll
    for (int kc = 0; kc < KC; ++kc)
        s += *(const f32x4*)(part + (((size_t)kc * OUT_NODES + j) * NBT + bt) * 1024 +
                             lane * 4);
    float sq = s[0] * s[0] + s[1] * s[1] + s[2] * s[2] + s[3] * s[3];
    sq += __shfl_xor(sq, 16);
    sq += __shfl_xor(sq, 32);
    float scale = sq / ((1.0f + sq) * sqrtf(sq));
    f32x4 vv = s * scale;
    const int b = bt * 16 + (lane & 15);
    const int d0 = (lane >> 4) * 4;

    // Bv[(j*8+bk)*64 + Ksub*16 + d][e]: bk=b>>5, Ksub=(b>>3)&3, e=b&7
    {
        const int bk = bt >> 1;
        const int Ksub = (bt & 1) * 2 + ((lane & 15) >> 3);
        const size_t base = (((size_t)j * 8 + bk) * 64 + Ksub * 16) * 8 + (lane & 7);
#pragma unroll
        for (int r = 0; r < 4; ++r)
            Bv[base + (size_t)(d0 + r) * 8] = f2bf(vv[r]);
    }
    if (write_out)
        *(f32x4*)(out + ((size_t)b * OUT_NODES + j) * OUT_DIM + d0) = vv;
}

// ---------------------------------------------------------------------------
// k_agree (MFMA): grid 288 (4 i's each), 256 thr = 4 waves.
// wave = (mt_l = w>>1, j-half = w&1). Per wave: M-tile = Axt x Bv (8 MFMA/j),
// contraction pa = sum_r C[r]*W[i,j,d,k0+r], 32-lane reduce -> a[i,j].
// Then softmax per i and c*W -> Ahi fold (validated layout).
// ---------------------------------------------------------------------------
__global__ __launch_bounds__(256) void k_agree(const float* __restrict__ W,
                                               const unsigned short* __restrict__ Axt,
                                               const unsigned short* __restrict__ Bv,
                                               float* __restrict__ blog,
                                               unsigned short* __restrict__ Ahi,
                                               int it) {
    __shared__ float a_s[4][OUT_NODES];
    __shared__ float csh[4][OUT_NODES];

    const int bid = blockIdx.x;          // 0..287
    const int tid = threadIdx.x;
    const int w = tid >> 6, lane = tid & 63;
    const int mt = bid * 2 + (w >> 1);   // this wave's m-tile (16 ik = 2 i's)
    const int jh = (w & 1) * 5;          // j half

    // A-frags for this m-tile (8 b-ktiles)
    bf16x8 af[8];
#pragma unroll
    for (int bk = 0; bk < 8; ++bk)
        af[bk] = *(const bf16x8*)(Axt + (((size_t)mt * 8 + bk) * 64 + lane) * 8);

    const int il = (w >> 1) * 2 + (lane >> 5);   // block-local i (0..3)
    const int i_g = bid * 4 + il;
    const int d = lane & 15;
    const int k0 = ((lane >> 4) & 1) * 4;

#pragma unroll
    for (int jl = 0; jl < 5; ++jl) {
        const int j = jh + jl;
        f32x4 acc = {0.f, 0.f, 0.f, 0.f};
#pragma unroll
        for (int bk = 0; bk < 8; ++bk) {
            bf16x8 bv = *(const bf16x8*)(Bv + (((size_t)j * 8 + bk) * 64 + lane) * 8);
            acc = __builtin_amdgcn_mfma_f32_16x16x32_bf16(af[bk], bv, acc, 0, 0, 0);
        }
        // contraction: C row = ik-sub = (lane>>4)*4+r -> k = k0+r, i = i_g
        float4 wv = *(const float4*)(W + (((size_t)i_g * OUT_NODES + j) * OUT_DIM + d) *
                                             IN_DIM + k0);
        float pa = acc[0] * wv.x + acc[1] * wv.y + acc[2] * wv.z + acc[3] * wv.w;
        pa += __shfl_xor(pa, 1);
        pa += __shfl_xor(pa, 2);
        pa += __shfl_xor(pa, 4);
        pa += __shfl_xor(pa, 8);
        pa += __shfl_xor(pa, 16);
        if ((lane & 31) == 0) a_s[il][j] = pa;
    }
    __syncthreads();

    if (tid < 4) {
        const int i = bid * 4 + tid;
        float bn[OUT_NODES];
        float m = -1e30f;
#pragma unroll
        for (int j = 0; j < OUT_NODES; ++j) {
            bn[j] = (it == 0 ? 0.f : blog[i * OUT_NODES + j]) +
                    a_s[tid][j] * (1.0f / BATCH);
            m = fmaxf(m, bn[j]);
        }
        float ex[OUT_NODES], ss = 0.f;
#pragma unroll
        for (int j = 0; j < OUT_NODES; ++j) { ex[j] = __expf(bn[j] - m); ss += ex[j]; }
        const float inv = 1.0f / ss;
#pragma unroll
        for (int j = 0; j < OUT_NODES; ++j) {
            if (it == 0) blog[i * OUT_NODES + j] = bn[j];
            csh[tid][j] = ex[j] * inv;
        }
    }
    __syncthreads();

    // fold c*W -> Ahi: 640 slots (4 i x 10 j x 16 d)
#pragma unroll
    for (int p = 0; p < 3; ++p) {
        const int q = p * 256 + tid;
        if (q < 640) {
            const int il2 = q / 160;
            const int rem = q % 160;
            const int j = rem >> 4;
            const int dd = rem & 15;
            const int i = bid * 4 + il2;
            const float c = csh[il2][j];
            const float4* wp = (const float4*)(W +
                (((size_t)i * OUT_NODES + j) * OUT_DIM + dd) * IN_DIM);
            float4 w0 = wp[0], w1 = wp[1];
            float vals[8] = {c * w0.x, c * w0.y, c * w0.z, c * w0.w,
                             c * w1.x, c * w1.y, c * w1.z, c * w1.w};
            bf16x8 vh;
#pragma unroll
            for (int e = 0; e < 8; ++e) vh[e] = (short)f2bf(vals[e]);
            size_t sl = ((size_t)j * KTILES + (i >> 2)) * 64 + (i & 3) * 16 + dd;
            *(bf16x8*)(Ahi + sl * 8) = vh;
        }
    }
}

// ---------------------------------------------------------------------------
extern "C" void kernel_launch(void* const* d_in, const int* in_sizes, int n_in,
                              void* d_out, int out_size, void* d_ws, size_t ws_size,
                              hipStream_t stream) {
    const float* x = (const float*)d_in[0];  // [256,1152,8]
    const float* W = (const float*)d_in[1];  // [1152,10,16,8]
    float* out = (float*)d_out;              // [256,10,16,1]

    char* p = (char*)d_ws;
    unsigned short* Bhi = (unsigned short*)p;  p += (size_t)NBT * KTILES * 64 * 8 * 2;  // 4.72 MB
    unsigned short* Ahi = (unsigned short*)p;  p += (size_t)OUT_NODES * KTILES * 64 * 8 * 2; // 2.95 MB
    unsigned short* Axt = (unsigned short*)p;  p += (size_t)MT * 8 * 64 * 8 * 2;        // 4.72 MB
    unsigned short* Bv  = (unsigned short*)p;  p += (size_t)OUT_NODES * 8 * 64 * 8 * 2; // 80 KB
    float* part = (float*)p;                   p += (size_t)KC * OUT_NODES * NBT * 1024 * 4; // 10.5 MB
    float* blog = (float*)p;                   p += (size_t)IN_NODES * OUT_NODES * 4;
    // total ~23 MB of ws

    k_prep<<<IN_NODES + 720 + 288, 256, 0, stream>>>(x, W, Bhi, Ahi, Axt);

    for (int it = 0; it < 3; ++it) {
        k_gemm<<<640, 256, 0, stream>>>(Ahi, Bhi, part);
        k_reduce<<<160, 64, 0, stream>>>(part, Bv, out, it == 2 ? 1 : 0);
        if (it < 2)
            k_agree<<<288, 256, 0, stream>>>(W, Axt, Bv, blog, Ahi, it);
    }
}

// Round 18
// 62.525 us; speedup vs baseline: 1.3695x; 1.0841x over previous
//
#include <hip/hip_runtime.h>
#include <math.h>

#define IN_NODES 1152
#define OUT_NODES 10
#define IN_DIM 8
#define OUT_DIM 16
#define BATCH 256
#define KTILES 288       // K = 9216 = 288 tiles of 32 (main GEMM)
#define KC 16            // split-K chunks
#define KT_PER_KC 18     // 288 / 16
#define NBT 16           // b-tiles of 16
#define MT 576           // m-tiles of 16 over ik = 9216 (agree M-GEMM)

typedef __attribute__((ext_vector_type(8))) short bf16x8;
typedef __attribute__((ext_vector_type(4))) float f32x4;

__device__ __forceinline__ unsigned short f2bf(float f) {
    unsigned u = __float_as_uint(f);
    u += 0x7FFF + ((u >> 16) & 1);   // round-to-nearest-even
    return (unsigned short)(u >> 16);
}

// ---------------------------------------------------------------------------
// Fragment conventions (validated r5/r8/r9/r10/r13/r14/r17):
//  A-frag: lane&15 = m, K = (lane>>4)*8 + e.   B-frag: lane&15 = n, same K.
//  C tile: col = lane&15 (n), row = (lane>>4)*4 + r (m).
// Packs:
//  Bhi  [bt][kt][lane][e]: n=b (lane&15), K=(i&3)*8+k       (main GEMM B)
//  Ahi  [j][kt][lane][e]:  m=d (lane&15), K=(i&3)*8+k       (main GEMM A)
//  Axt  [mt][bk][lane][e]: m=ik (lane&15), K=b&31           (M-GEMM A)
//  Bv   [j][bk][lane][e]:  n=d (lane&15),  K=b&31           (M-GEMM B)
// Precision: all packs bf16 RNE; r17 measured absmax 0.0039 (thr 0.0159).
// ---------------------------------------------------------------------------

// k_prep: [0,288): staged x-transpose -> Bhi + Axt (one block = i in
// [4n,4n+4) x all b = one Bhi kt-tile + one Axt mt-pair; coalesced reads,
// padded LDS, <=2-way bank aliasing).  [288,1008): Ahi (c = 0.1).
__global__ __launch_bounds__(256) void k_prep(const float* __restrict__ x,
                                              const float* __restrict__ W,
                                              unsigned short* __restrict__ Bhi,
                                              unsigned short* __restrict__ Ahi,
                                              unsigned short* __restrict__ Axt) {
    const int bid = blockIdx.x;
    const int tid = threadIdx.x;
    if (bid < 288) {
        __shared__ float xs[256][33];        // 33.8 KB, +1 pad
        const int n = bid;                   // i in [4n,4n+4), float off 32n

        // stage: 8 passes, 32 rows/pass, float4 per thread (coalesced)
#pragma unroll
        for (int p = 0; p < 8; ++p) {
            const int row = p * 32 + (tid >> 3);
            const int c4 = (tid & 7) * 4;
            float4 v = *(const float4*)(x + (size_t)row * (IN_NODES * IN_DIM) +
                                        n * 32 + c4);
            xs[row][c4] = v.x; xs[row][c4 + 1] = v.y;
            xs[row][c4 + 2] = v.z; xs[row][c4 + 3] = v.w;
        }
        __syncthreads();

        // Bhi: 1024 slots (16 bt x 64 lanes), kt = n
#pragma unroll
        for (int p = 0; p < 4; ++p) {
            const int q = p * 256 + tid;
            const int bt = q >> 6, lane = q & 63;
            const int b = bt * 16 + (lane & 15);
            const int il = lane >> 4;        // = i&3
            bf16x8 vh;
#pragma unroll
            for (int e = 0; e < 8; ++e) vh[e] = (short)f2bf(xs[b][il * 8 + e]);
            size_t sl = ((size_t)bt * KTILES + n) * 64 + lane;
            *(bf16x8*)(Bhi + sl * 8) = vh;
        }
        // Axt: 1024 slots (2 mt x 8 bk x 64 lanes)
#pragma unroll
        for (int p = 0; p < 4; ++p) {
            const int q = p * 256 + tid;
            const int mt_l = q >> 9, bk = (q >> 6) & 7, lane = q & 63;
            const int ik_l = mt_l * 16 + (lane & 15);
            const int b0 = bk * 32 + (lane >> 4) * 8;
            bf16x8 vh;
#pragma unroll
            for (int e = 0; e < 8; ++e) vh[e] = (short)f2bf(xs[b0 + e][ik_l]);
            const int mt = n * 2 + mt_l;
            *(bf16x8*)(Axt + (((size_t)mt * 8 + bk) * 64 + lane) * 8) = vh;
        }
    } else {
        const int s = (bid - 288) * 256 + tid;        // 0..184319
        const int j = s / (KTILES * 64);
        const int rem = s % (KTILES * 64);
        const int kt = rem >> 6;
        const int l = rem & 63;
        const int i = kt * 4 + (l >> 4);
        const int d = l & 15;
        const float4* wp = (const float4*)(W +
            (((size_t)i * OUT_NODES + j) * OUT_DIM + d) * IN_DIM);
        float4 w0 = wp[0], w1 = wp[1];
        const float c = 1.0f / OUT_NODES;
        float vals[8] = {c * w0.x, c * w0.y, c * w0.z, c * w0.w,
                         c * w1.x, c * w1.y, c * w1.z, c * w1.w};
        bf16x8 vh;
#pragma unroll
        for (int e = 0; e < 8; ++e) vh[e] = (short)f2bf(vals[e]);
        *(bf16x8*)(Ahi + (size_t)s * 8) = vh;
    }
}

// ---------------------------------------------------------------------------
// k_gemm: grid 640 = (j=10, btg=4, kc=16), 256 thr. (validated r14)
// ---------------------------------------------------------------------------
__global__ __launch_bounds__(256) void k_gemm(const unsigned short* __restrict__ Ahi,
                                              const unsigned short* __restrict__ Bhi,
                                              float* __restrict__ part) {
    const int bid = blockIdx.x;
    const int j = bid >> 6;
    const int r = bid & 63;
    const int btg = r >> 4;
    const int kc = r & 15;
    const int tid = threadIdx.x;
    const int lane = tid & 63;
    const int bt = btg * 4 + (tid >> 6);

    const size_t ab = (((size_t)j * KTILES + kc * KT_PER_KC) * 64 + lane) * 8;
    const size_t bb = (((size_t)bt * KTILES + kc * KT_PER_KC) * 64 + lane) * 8;

    f32x4 acc0 = {0.f, 0.f, 0.f, 0.f}, acc1 = acc0;
#pragma unroll
    for (int kt = 0; kt < KT_PER_KC; kt += 2) {
        bf16x8 a0 = *(const bf16x8*)(Ahi + ab + (size_t)kt * 512);
        bf16x8 b0 = *(const bf16x8*)(Bhi + bb + (size_t)kt * 512);
        bf16x8 a1 = *(const bf16x8*)(Ahi + ab + (size_t)(kt + 1) * 512);
        bf16x8 b1 = *(const bf16x8*)(Bhi + bb + (size_t)(kt + 1) * 512);
        acc0 = __builtin_amdgcn_mfma_f32_16x16x32_bf16(a0, b0, acc0, 0, 0, 0);
        acc1 = __builtin_amdgcn_mfma_f32_16x16x32_bf16(a1, b1, acc1, 0, 0, 0);
    }
    f32x4 acc = acc0 + acc1;
    *(f32x4*)(part + (((size_t)kc * OUT_NODES + j) * NBT + bt) * 1024 + lane * 4) = acc;
}

// ---------------------------------------------------------------------------
// k_reduce: grid 160 = (j,bt), 64 thr. Sum over kc + squash -> Bv + out.
// (validated r17)
// ---------------------------------------------------------------------------
__global__ __launch_bounds__(64) void k_reduce(const float* __restrict__ part,
                                               unsigned short* __restrict__ Bv,
                                               float* __restrict__ out,
                                               int write_out) {
    const int j = blockIdx.x >> 4;
    const int bt = blockIdx.x & 15;
    const int lane = threadIdx.x;

    f32x4 s = {0.f, 0.f, 0.f, 0.f};
#pragma unroll
    for (int kc = 0; kc < KC; ++kc)
        s += *(const f32x4*)(part + (((size_t)kc * OUT_NODES + j) * NBT + bt) * 1024 +
                             lane * 4);
    float sq = s[0] * s[0] + s[1] * s[1] + s[2] * s[2] + s[3] * s[3];
    sq += __shfl_xor(sq, 16);
    sq += __shfl_xor(sq, 32);
    float scale = sq / ((1.0f + sq) * sqrtf(sq));
    f32x4 vv = s * scale;
    const int b = bt * 16 + (lane & 15);
    const int d0 = (lane >> 4) * 4;

    {
        const int bk = bt >> 1;
        const int Ksub = (bt & 1) * 2 + ((lane & 15) >> 3);
        const size_t base = (((size_t)j * 8 + bk) * 64 + Ksub * 16) * 8 + (lane & 7);
#pragma unroll
        for (int r = 0; r < 4; ++r)
            Bv[base + (size_t)(d0 + r) * 8] = f2bf(vv[r]);
    }
    if (write_out)
        *(f32x4*)(out + ((size_t)b * OUT_NODES + j) * OUT_DIM + d0) = vv;
}

// ---------------------------------------------------------------------------
// k_agree (MFMA): grid 288 (4 i's each), 256 thr = 4 waves. (validated r17)
// ---------------------------------------------------------------------------
__global__ __launch_bounds__(256) void k_agree(const float* __restrict__ W,
                                               const unsigned short* __restrict__ Axt,
                                               const unsigned short* __restrict__ Bv,
                                               float* __restrict__ blog,
                                               unsigned short* __restrict__ Ahi,
                                               int it) {
    __shared__ float a_s[4][OUT_NODES];
    __shared__ float csh[4][OUT_NODES];

    const int bid = blockIdx.x;          // 0..287
    const int tid = threadIdx.x;
    const int w = tid >> 6, lane = tid & 63;
    const int mt = bid * 2 + (w >> 1);
    const int jh = (w & 1) * 5;

    bf16x8 af[8];
#pragma unroll
    for (int bk = 0; bk < 8; ++bk)
        af[bk] = *(const bf16x8*)(Axt + (((size_t)mt * 8 + bk) * 64 + lane) * 8);

    const int il = (w >> 1) * 2 + (lane >> 5);
    const int i_g = bid * 4 + il;
    const int d = lane & 15;
    const int k0 = ((lane >> 4) & 1) * 4;

#pragma unroll
    for (int jl = 0; jl < 5; ++jl) {
        const int j = jh + jl;
        f32x4 acc = {0.f, 0.f, 0.f, 0.f};
#pragma unroll
        for (int bk = 0; bk < 8; ++bk) {
            bf16x8 bv = *(const bf16x8*)(Bv + (((size_t)j * 8 + bk) * 64 + lane) * 8);
            acc = __builtin_amdgcn_mfma_f32_16x16x32_bf16(af[bk], bv, acc, 0, 0, 0);
        }
        float4 wv = *(const float4*)(W + (((size_t)i_g * OUT_NODES + j) * OUT_DIM + d) *
                                             IN_DIM + k0);
        float pa = acc[0] * wv.x + acc[1] * wv.y + acc[2] * wv.z + acc[3] * wv.w;
        pa += __shfl_xor(pa, 1);
        pa += __shfl_xor(pa, 2);
        pa += __shfl_xor(pa, 4);
        pa += __shfl_xor(pa, 8);
        pa += __shfl_xor(pa, 16);
        if ((lane & 31) == 0) a_s[il][j] = pa;
    }
    __syncthreads();

    if (tid < 4) {
        const int i = bid * 4 + tid;
        float bn[OUT_NODES];
        float m = -1e30f;
#pragma unroll
        for (int j = 0; j < OUT_NODES; ++j) {
            bn[j] = (it == 0 ? 0.f : blog[i * OUT_NODES + j]) +
                    a_s[tid][j] * (1.0f / BATCH);
            m = fmaxf(m, bn[j]);
        }
        float ex[OUT_NODES], ss = 0.f;
#pragma unroll
        for (int j = 0; j < OUT_NODES; ++j) { ex[j] = __expf(bn[j] - m); ss += ex[j]; }
        const float inv = 1.0f / ss;
#pragma unroll
        for (int j = 0; j < OUT_NODES; ++j) {
            if (it == 0) blog[i * OUT_NODES + j] = bn[j];
            csh[tid][j] = ex[j] * inv;
        }
    }
    __syncthreads();

#pragma unroll
    for (int p = 0; p < 3; ++p) {
        const int q = p * 256 + tid;
        if (q < 640) {
            const int il2 = q / 160;
            const int rem = q % 160;
            const int j = rem >> 4;
            const int dd = rem & 15;
            const int i = bid * 4 + il2;
            const float c = csh[il2][j];
            const float4* wp = (const float4*)(W +
                (((size_t)i * OUT_NODES + j) * OUT_DIM + dd) * IN_DIM);
            float4 w0 = wp[0], w1 = wp[1];
            float vals[8] = {c * w0.x, c * w0.y, c * w0.z, c * w0.w,
                             c * w1.x, c * w1.y, c * w1.z, c * w1.w};
            bf16x8 vh;
#pragma unroll
            for (int e = 0; e < 8; ++e) vh[e] = (short)f2bf(vals[e]);
            size_t sl = ((size_t)j * KTILES + (i >> 2)) * 64 + (i & 3) * 16 + dd;
            *(bf16x8*)(Ahi + sl * 8) = vh;
        }
    }
}

// ---------------------------------------------------------------------------
extern "C" void kernel_launch(void* const* d_in, const int* in_sizes, int n_in,
                              void* d_out, int out_size, void* d_ws, size_t ws_size,
                              hipStream_t stream) {
    const float* x = (const float*)d_in[0];  // [256,1152,8]
    const float* W = (const float*)d_in[1];  // [1152,10,16,8]
    float* out = (float*)d_out;              // [256,10,16,1]

    char* p = (char*)d_ws;
    unsigned short* Bhi = (unsigned short*)p;  p += (size_t)NBT * KTILES * 64 * 8 * 2;
    unsigned short* Ahi = (unsigned short*)p;  p += (size_t)OUT_NODES * KTILES * 64 * 8 * 2;
    unsigned short* Axt = (unsigned short*)p;  p += (size_t)MT * 8 * 64 * 8 * 2;
    unsigned short* Bv  = (unsigned short*)p;  p += (size_t)OUT_NODES * 8 * 64 * 8 * 2;
    float* part = (float*)p;                   p += (size_t)KC * OUT_NODES * NBT * 1024 * 4;
    float* blog = (float*)p;                   p += (size_t)IN_NODES * OUT_NODES * 4;
    // total ~23 MB of ws

    k_prep<<<288 + 720, 256, 0, stream>>>(x, W, Bhi, Ahi, Axt);

    for (int it = 0; it < 3; ++it) {
        k_gemm<<<640, 256, 0, stream>>>(Ahi, Bhi, part);
        k_reduce<<<160, 64, 0, stream>>>(part, Bv, out, it == 2 ? 1 : 0);
        if (it < 2)
            k_agree<<<288, 256, 0, stream>>>(W, Axt, Bv, blog, Ahi, it);
    }
}